// Round 6
// baseline (321.708 us; speedup 1.0000x reference)
//
#include <hip/hip_runtime.h>
#include <math.h>

// ---------------------------------------------------------------------------
// GCN: 4x (bf16-MFMA GEMM (epilogue pre-scales rows by dis) ->
//          pure-sum aggregation (+bias, lrelu)) -> softmax.
// Graph prep per call (bucketed, LDS-local):
//   bin edges by dst>>8 -> per-bucket degree+dis -> scan -> bucket CSR in LDS.
// out[n] = dis[n]*( sum_e h'[s] + h'[n] ) + b,  h'[r] = dis[r]*(h@W)[r]
// Aggregation: quarter-split uint4 gathers (1 VMEM = 4 rows x 256B/4).
// ---------------------------------------------------------------------------

typedef unsigned short ushort_t;
typedef unsigned int   uint_t;
typedef short  bf16x8 __attribute__((ext_vector_type(8)));
typedef float  f32x4  __attribute__((ext_vector_type(4)));

#define BKT_SHIFT 8               // 256 nodes per bucket
#define BKT_CAP   5120            // >= max edges per bucket (mean 4096, +16 sigma)
#define BIN_CHUNK 4096            // edges per bin workgroup

__device__ __forceinline__ ushort_t f2bf(float f) {
    union { float f; uint_t u; } v; v.f = f;
    uint_t u = v.u;
    u += 0x7fffu + ((u >> 16) & 1u);      // round-to-nearest-even
    return (ushort_t)(u >> 16);
}
__device__ __forceinline__ float bflo(uint_t u) {
    union { uint_t q; float f; } v; v.q = u << 16; return v.f;
}
__device__ __forceinline__ float bfhi(uint_t u) {
    union { uint_t q; float f; } v; v.q = u & 0xffff0000u; return v.f;
}

// ------------------------------- graph prep -------------------------------

__global__ __launch_bounds__(256) void bin_kernel(const int* __restrict__ srcArr,
                                                  const int* __restrict__ dstArr,
                                                  int* __restrict__ bkt_cursor,
                                                  uint2* __restrict__ staging,
                                                  int E, int nb) {
    __shared__ int hist[512];
    __shared__ int base[512];
    for (int b = threadIdx.x; b < 512; b += 256) hist[b] = 0;
    __syncthreads();
    const int e0 = blockIdx.x * BIN_CHUNK;
    #pragma unroll 4
    for (int k = 0; k < BIN_CHUNK / 256; ++k) {
        int e = e0 + k * 256 + threadIdx.x;
        if (e < E) atomicAdd(&hist[dstArr[e] >> BKT_SHIFT], 1);
    }
    __syncthreads();
    for (int b = threadIdx.x; b < nb; b += 256) {
        int h = hist[b];
        base[b] = h ? atomicAdd(&bkt_cursor[b], h) : 0;
    }
    __syncthreads();
    for (int b = threadIdx.x; b < 512; b += 256) hist[b] = 0;  // reuse as cursor
    __syncthreads();
    #pragma unroll 4
    for (int k = 0; k < BIN_CHUNK / 256; ++k) {
        int e = e0 + k * 256 + threadIdx.x;
        if (e < E) {
            int s = srcArr[e], d = dstArr[e];
            int b = d >> BKT_SHIFT;
            int p = atomicAdd(&hist[b], 1);
            int idx = base[b] + p;
            if (idx < BKT_CAP)
                staging[(size_t)b * BKT_CAP + idx] = make_uint2((uint_t)s, (uint_t)d);
        }
    }
}

// per-bucket degree count (LDS-local) + dis = rsqrt(deg+1), coalesced writes
__global__ __launch_bounds__(256) void deg_from_staging_kernel(const uint2* __restrict__ staging,
                                                               const int* __restrict__ bkt_cursor,
                                                               int* __restrict__ degi,
                                                               float* __restrict__ dis, int n) {
    __shared__ int cur[256];
    const int b  = blockIdx.x;
    const int lo = b << BKT_SHIFT;
    const int nl = min(256, n - lo);
    cur[threadIdx.x] = 0;
    __syncthreads();
    int cnt = min(bkt_cursor[b], BKT_CAP);
    for (int e = threadIdx.x; e < cnt; e += 256) {
        uint2 p = staging[(size_t)b * BKT_CAP + e];
        atomicAdd(&cur[(int)p.y - lo], 1);
    }
    __syncthreads();
    if ((int)threadIdx.x < nl) {
        int d = cur[threadIdx.x];
        degi[lo + threadIdx.x] = d;
        dis[lo + threadIdx.x] = rsqrtf((float)(d + 1));
    }
}

// hierarchical exclusive scan
__global__ void scan_block_kernel(const int* __restrict__ degi, int* __restrict__ row_excl,
                                  int* __restrict__ bsums, int n) {
    __shared__ int buf[1024];
    int i = blockIdx.x * 1024 + threadIdx.x;
    int v = (i < n) ? degi[i] : 0;
    buf[threadIdx.x] = v;
    __syncthreads();
    for (int off = 1; off < 1024; off <<= 1) {
        int t = (threadIdx.x >= (unsigned)off) ? buf[threadIdx.x - off] : 0;
        __syncthreads();
        buf[threadIdx.x] += t;
        __syncthreads();
    }
    if (i < n) row_excl[i] = buf[threadIdx.x] - v;
    if (threadIdx.x == 1023) bsums[blockIdx.x] = buf[1023];
}

__global__ void scan_sums_kernel(int* __restrict__ bsums, int nb) {
    __shared__ int buf[128];
    int v = ((int)threadIdx.x < nb) ? bsums[threadIdx.x] : 0;
    buf[threadIdx.x] = v;
    __syncthreads();
    for (int off = 1; off < 128; off <<= 1) {
        int t = (threadIdx.x >= (unsigned)off) ? buf[threadIdx.x - off] : 0;
        __syncthreads();
        buf[threadIdx.x] += t;
        __syncthreads();
    }
    if ((int)threadIdx.x < nb) bsums[threadIdx.x] = buf[threadIdx.x] - v;
    if (threadIdx.x == 0) bsums[nb] = buf[127];
}

__global__ void scan_add_kernel(int* __restrict__ row_start, const int* __restrict__ bsums,
                                int n, int nb) {
    int i = blockIdx.x * blockDim.x + threadIdx.x;
    if (i < n) row_start[i] += bsums[i >> 10];
    else if (i == n) row_start[n] = bsums[nb];
}

// build each bucket's CSR segment in LDS, flush coalesced
__global__ __launch_bounds__(256) void csr_build_kernel(const uint2* __restrict__ staging,
                                                        const int* __restrict__ bkt_cursor,
                                                        const int* __restrict__ row_start,
                                                        int* __restrict__ csr_src, int n) {
    __shared__ int rs[257];
    __shared__ int cur[256];
    __shared__ int seg[BKT_CAP];
    const int b  = blockIdx.x;
    const int lo = b << BKT_SHIFT;
    const int nl = min(256, n - lo);
    if ((int)threadIdx.x <= nl) rs[threadIdx.x] = row_start[lo + threadIdx.x];
    cur[threadIdx.x] = 0;
    __syncthreads();
    const int sbase = rs[0];
    int cnt = min(bkt_cursor[b], BKT_CAP);
    for (int e = threadIdx.x; e < cnt; e += 256) {
        uint2 p = staging[(size_t)b * BKT_CAP + e];
        int ln = (int)p.y - lo;
        int q  = atomicAdd(&cur[ln], 1);
        seg[(rs[ln] - sbase) + q] = (int)p.x;
    }
    __syncthreads();
    for (int i = threadIdx.x; i < cnt; i += 256) csr_src[sbase + i] = seg[i];
}

// -------------------- weight transposes (one kernel) -----------------------
__global__ void wt_all_kernel(const float* __restrict__ W1, const float* __restrict__ W2,
                              const float* __restrict__ W3,
                              ushort_t* __restrict__ Wt1, ushort_t* __restrict__ Wt2,
                              ushort_t* __restrict__ Wt3) {
    int idx = blockIdx.x * blockDim.x + threadIdx.x;
    if (idx < 32768) {
        int nn = idx >> 8, k = idx & 255;
        Wt1[idx] = f2bf(W1[(size_t)k * 128 + nn]);
    } else if (idx < 49152) {
        int j = idx - 32768;
        int nn = j >> 7, k = j & 127;
        float v = (nn < 100) ? W2[(size_t)k * 100 + nn] : 0.f;
        Wt2[j] = f2bf(v);
    } else if (idx < 57344) {
        int j = idx - 49152;
        int nn = j >> 7, k = j & 127;
        float v = (k < 100 && nn < 32) ? W3[(size_t)k * 32 + nn] : 0.f;
        Wt3[j] = f2bf(v);
    }
}

// ------------------------------ MFMA GEMM ---------------------------------
// C[M x nstore] (bf16) = dis[row] * (A[M x K] @ Bt[NP x K]^T).
// BM=128, BN = NFR*32 (NFR frags of 16 per wave in N), BK=64, 4 waves (2Mx2N).
template <bool A_FP32, int NFR>
__global__ __launch_bounds__(256) void mfma_gemm(const void* __restrict__ Av,
                                                 const ushort_t* __restrict__ Bt,
                                                 ushort_t* __restrict__ C,
                                                 const float* __restrict__ dis,
                                                 int M, int K, int lda, int ldb,
                                                 int ldc, int nstore) {
    constexpr int BN = NFR * 32;
    __shared__ __attribute__((aligned(16))) ushort_t As[128][72];  // +8 pad
    __shared__ __attribute__((aligned(16))) ushort_t Bs[BN][72];

    const int t    = threadIdx.x;
    const int lane = t & 63;
    const int w    = t >> 6;
    const int wm   = w >> 1, wn = w & 1;
    const int m0   = blockIdx.x * 128;
    const int n0   = blockIdx.y * BN;

    f32x4 acc[4][NFR];
    #pragma unroll
    for (int mi = 0; mi < 4; ++mi)
        #pragma unroll
        for (int ni = 0; ni < NFR; ++ni) acc[mi][ni] = (f32x4){0.f, 0.f, 0.f, 0.f};

    const int srow = t >> 3;          // 0..31
    const int scol = (t & 7) * 8;     // 0..56

    for (int k0 = 0; k0 < K; k0 += 64) {
        #pragma unroll
        for (int it = 0; it < 4; ++it) {            // A tile 128x64
            int r = srow + it * 32;
            int gm = m0 + r;
            bf16x8 v = {0, 0, 0, 0, 0, 0, 0, 0};
            if (gm < M) {
                if (A_FP32) {
                    const float* A = (const float*)Av;
                    const float4 f0 = *(const float4*)(A + (size_t)gm * lda + k0 + scol);
                    const float4 f1 = *(const float4*)(A + (size_t)gm * lda + k0 + scol + 4);
                    ushort_t o[8] = { f2bf(f0.x), f2bf(f0.y), f2bf(f0.z), f2bf(f0.w),
                                      f2bf(f1.x), f2bf(f1.y), f2bf(f1.z), f2bf(f1.w) };
                    v = *(const bf16x8*)o;
                } else {
                    const ushort_t* A = (const ushort_t*)Av;
                    v = *(const bf16x8*)(A + (size_t)gm * lda + k0 + scol);
                }
            }
            *(bf16x8*)&As[r][scol] = v;
        }
        #pragma unroll
        for (int it = 0; it < BN / 32; ++it) {      // B tile BNx64
            int r = srow + it * 32;
            bf16x8 v = *(const bf16x8*)(Bt + (size_t)(n0 + r) * ldb + k0 + scol);
            *(bf16x8*)&Bs[r][scol] = v;
        }
        __syncthreads();
        #pragma unroll
        for (int kk = 0; kk < 2; ++kk) {
            bf16x8 af[4], bfr[NFR];
            const int kc = kk * 32 + (lane >> 4) * 8;
            #pragma unroll
            for (int mi = 0; mi < 4; ++mi)
                af[mi] = *(const bf16x8*)&As[wm * 64 + mi * 16 + (lane & 15)][kc];
            #pragma unroll
            for (int ni = 0; ni < NFR; ++ni)
                bfr[ni] = *(const bf16x8*)&Bs[wn * (BN / 2) + ni * 16 + (lane & 15)][kc];
            #pragma unroll
            for (int mi = 0; mi < 4; ++mi)
                #pragma unroll
                for (int ni = 0; ni < NFR; ++ni)
                    acc[mi][ni] = __builtin_amdgcn_mfma_f32_16x16x32_bf16(
                        af[mi], bfr[ni], acc[mi][ni], 0, 0, 0);
        }
        __syncthreads();
    }

    // C/D layout: col = lane&15, row = (lane>>4)*4 + r; pre-scale by dis[row]
    #pragma unroll
    for (int mi = 0; mi < 4; ++mi)
        #pragma unroll
        for (int r = 0; r < 4; ++r) {
            int gm = m0 + wm * 64 + mi * 16 + (lane >> 4) * 4 + r;
            if (gm >= M) continue;
            float d = dis[gm];
            #pragma unroll
            for (int ni = 0; ni < NFR; ++ni) {
                int gn = n0 + wn * (BN / 2) + ni * 16 + (lane & 15);
                if (gn < nstore)
                    C[(size_t)gm * ldc + gn] = f2bf(acc[mi][ni][r] * d);
            }
        }
}

// ---------------------------- aggregation ---------------------------------
// h rows pre-scaled (h' = dis*h). One wave per node. Quarter-split:
// lanes (l&15) cover features fb = (l&15)*8 (one uint4 = 8 bf16 = 16B),
// quarter q = l>>4 takes edge i+q; one VMEM gather = 4 rows x 256B/4 = 1KB.
template <int F>
__global__ void aggregate128_kernel(const ushort_t* __restrict__ h, const int* __restrict__ row_start,
                                    const int* __restrict__ csr_src,
                                    const float* __restrict__ dis, const float* __restrict__ bias,
                                    ushort_t* __restrict__ out, int n) {
    int wid  = threadIdx.x >> 6;
    int lane = threadIdx.x & 63;
    int node = blockIdx.x * 4 + wid;
    if (node >= n) return;
    const int q  = lane >> 4;
    const int fb = (lane & 15) * 8;
    float a[8];
    #pragma unroll
    for (int j = 0; j < 8; ++j) a[j] = 0.f;

    int i = row_start[node], end = row_start[node + 1];

#define ACC8(U)                                                     \
    do {                                                            \
        a[0] += bflo((U).x); a[1] += bfhi((U).x);                   \
        a[2] += bflo((U).y); a[3] += bfhi((U).y);                   \
        a[4] += bflo((U).z); a[5] += bfhi((U).z);                   \
        a[6] += bflo((U).w); a[7] += bfhi((U).w);                   \
    } while (0)

    #pragma unroll 2
    for (; i + 8 <= end; i += 8) {
        int sA = csr_src[i + q];
        int sB = csr_src[i + 4 + q];
        uint4 u = *(const uint4*)(h + (size_t)sA * 128 + fb);
        uint4 v = *(const uint4*)(h + (size_t)sB * 128 + fb);
        ACC8(u);
        ACC8(v);
    }
    int r = end - i;
    if (r > 0) {
        if (q < r) {
            int sA = csr_src[i + q];
            uint4 u = *(const uint4*)(h + (size_t)sA * 128 + fb);
            ACC8(u);
        }
        if (q + 4 < r) {
            int sB = csr_src[i + 4 + q];
            uint4 v = *(const uint4*)(h + (size_t)sB * 128 + fb);
            ACC8(v);
        }
    }
#undef ACC8

    // merge quarters: q0+=q1 (xor16), then +=q2/q3 (xor32)
    #pragma unroll
    for (int j = 0; j < 8; ++j) {
        a[j] += __shfl_xor(a[j], 16);
        a[j] += __shfl_xor(a[j], 32);
    }

    if (q == 0) {
        uint4 su = *(const uint4*)(h + (size_t)node * 128 + fb);   // self-loop
        a[0] += bflo(su.x); a[1] += bfhi(su.x);
        a[2] += bflo(su.y); a[3] += bfhi(su.y);
        a[4] += bflo(su.z); a[5] += bfhi(su.z);
        a[6] += bflo(su.w); a[7] += bfhi(su.w);
        float dn = dis[node];
        #pragma unroll
        for (int j = 0; j < 8; ++j) {
            float b = (fb + j < F) ? bias[fb + j] : 0.f;
            float v = a[j] * dn + b;
            v = (v > 0.f) ? v : 0.1f * v;
            if (fb + j >= F) v = 0.f;          // keep K-padding exactly zero
            a[j] = v;
        }
        uint4 o;
        o.x = (uint_t)f2bf(a[0]) | ((uint_t)f2bf(a[1]) << 16);
        o.y = (uint_t)f2bf(a[2]) | ((uint_t)f2bf(a[3]) << 16);
        o.z = (uint_t)f2bf(a[4]) | ((uint_t)f2bf(a[5]) << 16);
        o.w = (uint_t)f2bf(a[6]) | ((uint_t)f2bf(a[7]) << 16);
        *(uint4*)(out + (size_t)node * 128 + fb) = o;
    }
}

// F=32, h pre-scaled: 16-lane group per node (2 features/lane), 4 nodes/wave
__global__ void aggregate32_kernel(const ushort_t* __restrict__ h, const int* __restrict__ row_start,
                                   const int* __restrict__ csr_src,
                                   const float* __restrict__ dis, const float* __restrict__ bias,
                                   ushort_t* __restrict__ out, int n) {
    int lane16 = threadIdx.x & 15;
    int node = blockIdx.x * (blockDim.x >> 4) + (threadIdx.x >> 4);
    if (node >= n) return;
    const int f0 = 2 * lane16;
    uint_t v = *(const uint_t*)(h + (size_t)node * 32 + f0);
    float acc0 = bflo(v);               // self-loop (pre-scaled)
    float acc1 = bfhi(v);
    int i = row_start[node], end = row_start[node + 1];
    for (; i + 4 <= end; i += 4) {
        int s0 = csr_src[i], s1 = csr_src[i + 1], s2 = csr_src[i + 2], s3 = csr_src[i + 3];
        uint_t u0 = *(const uint_t*)(h + (size_t)s0 * 32 + f0);
        uint_t u1 = *(const uint_t*)(h + (size_t)s1 * 32 + f0);
        uint_t u2 = *(const uint_t*)(h + (size_t)s2 * 32 + f0);
        uint_t u3 = *(const uint_t*)(h + (size_t)s3 * 32 + f0);
        acc0 += bflo(u0) + bflo(u1) + bflo(u2) + bflo(u3);
        acc1 += bfhi(u0) + bfhi(u1) + bfhi(u2) + bfhi(u3);
    }
    for (; i < end; ++i) {
        int s = csr_src[i];
        uint_t u = *(const uint_t*)(h + (size_t)s * 32 + f0);
        acc0 += bflo(u); acc1 += bfhi(u);
    }
    float dn = dis[node];
    acc0 = acc0 * dn + bias[f0];
    acc1 = acc1 * dn + bias[f0 + 1];
    acc0 = (acc0 > 0.f) ? acc0 : 0.1f * acc0;
    acc1 = (acc1 > 0.f) ? acc1 : 0.1f * acc1;
    uint_t o = (uint_t)f2bf(acc0) | ((uint_t)f2bf(acc1) << 16);
    *(uint_t*)(out + (size_t)node * 32 + f0) = o;
}

// layer 4 GEMM: [N x 32] bf16 @ [32 x 2] fp32 -> fp32, pre-scaled by dis[node]
__global__ void gemm32x2_kernel(const ushort_t* __restrict__ H, const float* __restrict__ W4,
                                const float* __restrict__ dis, float* __restrict__ C, int n) {
    int node = blockIdx.x * blockDim.x + threadIdx.x;
    if (node >= n) return;
    const uint_t* row = (const uint_t*)(H + (size_t)node * 32);
    float a0 = 0.f, a1 = 0.f;
    #pragma unroll
    for (int k2 = 0; k2 < 16; ++k2) {
        uint_t u = row[k2];
        float x0 = bflo(u), x1 = bfhi(u);
        int k = 2 * k2;
        a0 += x0 * W4[k * 2]     + x1 * W4[(k + 1) * 2];
        a1 += x0 * W4[k * 2 + 1] + x1 * W4[(k + 1) * 2 + 1];
    }
    float d = dis[node];
    C[2 * (size_t)node]     = a0 * d;
    C[2 * (size_t)node + 1] = a1 * d;
}

// final aggregation (F=2, h pre-scaled) + bias + softmax, one thread per node
__global__ void aggregate2_softmax_kernel(const float* __restrict__ h, const int* __restrict__ row_start,
                                          const int* __restrict__ csr_src,
                                          const float* __restrict__ dis, const float* __restrict__ bias,
                                          float* __restrict__ out, int n) {
    int node = blockIdx.x * blockDim.x + threadIdx.x;
    if (node >= n) return;
    float a0 = h[2 * (size_t)node];
    float a1 = h[2 * (size_t)node + 1];
    int beg = row_start[node], end = row_start[node + 1];
    for (int i = beg; i < end; ++i) {
        int s = csr_src[i];
        a0 += h[2 * (size_t)s];
        a1 += h[2 * (size_t)s + 1];
    }
    float dn = dis[node];
    a0 = a0 * dn + bias[0];
    a1 = a1 * dn + bias[1];
    float m  = fmaxf(a0, a1);
    float e0 = expf(a0 - m), e1 = expf(a1 - m);
    float inv = 1.f / (e0 + e1);
    out[2 * (size_t)node]     = e0 * inv;
    out[2 * (size_t)node + 1] = e1 * inv;
}

// ---------------------------------------------------------------------------

extern "C" void kernel_launch(void* const* d_in, const int* in_sizes, int n_in,
                              void* d_out, int out_size, void* d_ws, size_t ws_size,
                              hipStream_t stream) {
    const float* x  = (const float*)d_in[0];
    const int*   ei = (const int*)d_in[1];
    const float* W1 = (const float*)d_in[2];
    const float* b1 = (const float*)d_in[3];
    const float* W2 = (const float*)d_in[4];
    const float* b2 = (const float*)d_in[5];
    const float* W3 = (const float*)d_in[6];
    const float* b3 = (const float*)d_in[7];
    const float* W4 = (const float*)d_in[8];
    const float* b4 = (const float*)d_in[9];

    const int N = in_sizes[0] / 256;
    const int E = in_sizes[1] / 2;
    const int* srcA = ei;
    const int* dstA = ei + E;
    const int nbkt = (N + 255) >> BKT_SHIFT;

    char* ws = (char*)d_ws;
    size_t off = 0;
    auto alloc = [&](size_t bytes) {
        void* p = ws + off;
        off = (off + bytes + 255) & ~(size_t)255;
        return p;
    };
    int*      degi       = (int*)alloc((size_t)N * 4);
    float*    dis        = (float*)alloc((size_t)N * 4);
    int*      row_start  = (int*)alloc((size_t)(N + 1) * 4);
    int*      bsums      = (int*)alloc(512 * 4);
    int*      bkt_cursor = (int*)alloc((size_t)nbkt * 4);
    int*      csr_src    = (int*)alloc((size_t)E * 4);
    uint2*    staging    = (uint2*)alloc((size_t)nbkt * BKT_CAP * 8);
    ushort_t* bufA       = (ushort_t*)alloc((size_t)N * 128 * 2);
    ushort_t* bufB       = (ushort_t*)alloc((size_t)N * 128 * 2);
    float*    C4         = (float*)alloc((size_t)N * 2 * 4);
    ushort_t* Wt1        = (ushort_t*)alloc((size_t)128 * 256 * 2);
    ushort_t* Wt2        = (ushort_t*)alloc((size_t)128 * 128 * 2);
    ushort_t* Wt3        = (ushort_t*)alloc((size_t)64 * 128 * 2);
    (void)ws_size;

    hipMemsetAsync(bkt_cursor, 0, (size_t)nbkt * 4, stream);

    // graph prep (bucketed)
    bin_kernel<<<(E + BIN_CHUNK - 1) / BIN_CHUNK, 256, 0, stream>>>(
        srcA, dstA, bkt_cursor, staging, E, nbkt);
    deg_from_staging_kernel<<<nbkt, 256, 0, stream>>>(staging, bkt_cursor, degi, dis, N);
    const int nb = (N + 1023) >> 10;
    scan_block_kernel<<<nb, 1024, 0, stream>>>(degi, row_start, bsums, N);
    scan_sums_kernel<<<1, 128, 0, stream>>>(bsums, nb);
    scan_add_kernel<<<(N + 256) / 256, 256, 0, stream>>>(row_start, bsums, N, nb);
    csr_build_kernel<<<nbkt, 256, 0, stream>>>(staging, bkt_cursor, row_start, csr_src, N);

    // weight transposes (bf16, padded) — one kernel
    wt_all_kernel<<<(57344 + 255) / 256, 256, 0, stream>>>(W1, W2, W3, Wt1, Wt2, Wt3);

    const int gx = (N + 127) / 128;
    const int aggBlocks128 = (N + 3) / 4;    // 4 waves/block, 1 node/wave
    const int aggBlocks32  = (N + 15) / 16;  // 16 nodes/block

    // layer 1: 256 -> 128 (A fp32 converted in staging; BN=128 single pass)
    mfma_gemm<true, 4><<<dim3(gx, 1), 256, 0, stream>>>(x, Wt1, bufA, dis, N, 256, 256, 256, 128, 128);
    aggregate128_kernel<128><<<aggBlocks128, 256, 0, stream>>>(
        bufA, row_start, csr_src, dis, b1, bufB, N);
    // layer 2: 128 -> 100 (padded), BN=128 single pass
    mfma_gemm<false, 4><<<dim3(gx, 1), 256, 0, stream>>>(bufB, Wt2, bufA, dis, N, 128, 128, 128, 128, 128);
    aggregate128_kernel<100><<<aggBlocks128, 256, 0, stream>>>(
        bufA, row_start, csr_src, dis, b2, bufB, N);
    // layer 3: 128(pad) -> 32, BN=64
    mfma_gemm<false, 2><<<dim3(gx, 1), 256, 0, stream>>>(bufB, Wt3, bufA, dis, N, 128, 128, 128, 32, 32);
    aggregate32_kernel<<<aggBlocks32, 256, 0, stream>>>(
        bufA, row_start, csr_src, dis, b3, bufB, N);
    // layer 4: 32 -> 2, aggregate + softmax
    gemm32x2_kernel<<<(N + 255) / 256, 256, 0, stream>>>(bufB, W4, dis, C4, N);
    aggregate2_softmax_kernel<<<(N + 255) / 256, 256, 0, stream>>>(
        C4, row_start, csr_src, dis, b4, (float*)d_out, N);
}